// Round 5
// baseline (6013.586 us; speedup 1.0000x reference)
//
#include <hip/hip_runtime.h>
#include <hip/hip_bf16.h>

typedef __hip_bfloat16 bf16;
typedef float fx2 __attribute__((ext_vector_type(2)));

#define NL 4096      // L leaves
#define NH 128       // H hidden
#define NE 256       // E embed
#define NT 64        // T tags
#define NNODE 8191   // N = 2L-1
#define NDEPTH 12    // D = log2(L)

// converted f32 weights, offsets into wf[] (floats)
#define OF_WIH   0
#define OF_WHH   131072
#define OF_BIH   196608
#define OF_BHH   197120
#define OF_WP2H  197632
#define OF_BP2H  230400
#define OF_WUNI  230528
#define OF_BUNI  238720
#define OF_WEDGE 238784
#define OF_BEDGE 1287360
#define WF_TOTAL 1291456

__device__ __forceinline__ float b2f(bf16 x) { return __bfloat162float(x); }

// ------------------------------------------------ dtype detection
__global__ void detect_kernel(const void* __restrict__ wedge_raw, int* __restrict__ flag) {
  __shared__ int cnt_sh[256];
  const unsigned short* p = (const unsigned short*)wedge_raw;
  int c = 0;
  for (int i = threadIdx.x; i < 32768; i += 256) {
    float v = __uint_as_float(((unsigned)p[2 * i]) << 16);
    if (fabsf(v) > 4.f) c++;
  }
  cnt_sh[threadIdx.x] = c;
  __syncthreads();
  for (int s = 128; s > 0; s >>= 1) {
    if (threadIdx.x < s) cnt_sh[threadIdx.x] += cnt_sh[threadIdx.x + s];
    __syncthreads();
  }
  if (threadIdx.x == 0) *flag = cnt_sh[0];   // >100 => inputs are f32
}

// ------------------------------------------------ convert all weights -> f32 in ws
__global__ void convert_kernel(const void* s0, const void* s1, const void* s2, const void* s3,
                               const void* s4, const void* s5, const void* s6, const void* s7,
                               const void* s8, const void* s9,
                               const int* __restrict__ flag, float* __restrict__ wf) {
  int i = blockIdx.x * 256 + threadIdx.x;
  if (i >= WF_TOTAL) return;
  const void* src; int local;
  if      (i < OF_WHH)   { src = s0; local = i; }
  else if (i < OF_BIH)   { src = s1; local = i - OF_WHH; }
  else if (i < OF_BHH)   { src = s2; local = i - OF_BIH; }
  else if (i < OF_WP2H)  { src = s3; local = i - OF_BHH; }
  else if (i < OF_BP2H)  { src = s4; local = i - OF_WP2H; }
  else if (i < OF_WUNI)  { src = s5; local = i - OF_BP2H; }
  else if (i < OF_BUNI)  { src = s6; local = i - OF_WUNI; }
  else if (i < OF_WEDGE) { src = s7; local = i - OF_BUNI; }
  else if (i < OF_BEDGE) { src = s8; local = i - OF_WEDGE; }
  else                   { src = s9; local = i - OF_BEDGE; }
  bool isf32 = (*flag) > 100;
  wf[i] = isf32 ? ((const float*)src)[local] : b2f(((const bf16*)src)[local]);
}

// ------------------------------------------------ G1 = emb[tok]@W_ih^T + b_ih + b_hh
// Output layout is gate-interleaved: G1[t][hrow*4 + gate] so the LSTM's
// phase-B thread j reads one float4 = {i,f,g,o} for its h-row.
__global__ __launch_bounds__(512) void g1_kernel(const int* __restrict__ tokens,
                                                 const void* __restrict__ emb_raw,
                                                 const int* __restrict__ flag,
                                                 const float* __restrict__ wf,
                                                 float* __restrict__ G1) {
  __shared__ __attribute__((aligned(16))) float xs[8 * NE];
  const bool isf32 = (*flag) > 100;
  const int t0 = blockIdx.x * 8;
  for (int q = threadIdx.x; q < 8 * NE; q += 512) {
    int tok = q >> 8, e = q & 255;
    size_t off = (size_t)tokens[t0 + tok] * NE + e;
    xs[q] = isf32 ? ((const float*)emb_raw)[off] : b2f(((const bf16*)emb_raw)[off]);
  }
  __syncthreads();
  const int r = threadIdx.x;                 // gate row 0..511
  const float bias = wf[OF_BIH + r] + wf[OF_BHH + r];
  float acc[8];
#pragma unroll
  for (int k = 0; k < 8; ++k) acc[k] = bias;
  const float4* W4 = (const float4*)(wf + OF_WIH + (size_t)r * NE);
#pragma unroll 8
  for (int j = 0; j < 64; ++j) {
    float4 wv = W4[j];
#pragma unroll
    for (int tok = 0; tok < 8; ++tok) {
      float4 xv = ((const float4*)(xs + tok * NE))[j];   // wave-uniform broadcast
      acc[tok] += wv.x * xv.x + wv.y * xv.y + wv.z * xv.z + wv.w * xv.w;
    }
  }
  const int gi = (r & 127) * 4 + (r >> 7);   // gate-interleaved slot
#pragma unroll
  for (int tok = 0; tok < 8; ++tok) G1[(size_t)(t0 + tok) * 512 + gi] = acc[tok];
}

// ------------------------------------------------ sequential LSTM, 1 block, 256 threads
// Weight residency via HARDCODED AGPRs a0..a255: rounds 0-4 proved the
// register allocator will not hold loop-invariant weights in VGPRs (it
// remats from L2 or spills pinned values to scratch => 256 KB/step L2
// traffic ~= 2000 cyc/step, the invariant cost). Hardcoded v_accvgpr_write/
// read bypasses the allocator entirely; the entry clobber forces AGPR
// allocation in the kernel descriptor. Per MAC: 1 v_accvgpr_read + 1 fma
// (register-file bandwidth only, no memory traffic).
__global__ __launch_bounds__(256, 1) void lstm_kernel(const float* __restrict__ wf,
                                                      const float* __restrict__ G1,
                                                      float* __restrict__ hidden) {
  const int tid = threadIdx.x;               // 0..255
  const int j   = tid & 127;                 // h-row
  const int kh  = tid >> 7;                  // k-half (wave-uniform)
  __shared__ __attribute__((aligned(16))) float h_sh[NH];
  __shared__ __attribute__((aligned(16))) float part_sh[256][4];

  // Reserve + force allocation of a0..a255.
  asm volatile("" :::
    "a0","a1","a2","a3","a4","a5","a6","a7","a8","a9","a10","a11","a12","a13","a14","a15",
    "a16","a17","a18","a19","a20","a21","a22","a23","a24","a25","a26","a27","a28","a29","a30","a31",
    "a32","a33","a34","a35","a36","a37","a38","a39","a40","a41","a42","a43","a44","a45","a46","a47",
    "a48","a49","a50","a51","a52","a53","a54","a55","a56","a57","a58","a59","a60","a61","a62","a63",
    "a64","a65","a66","a67","a68","a69","a70","a71","a72","a73","a74","a75","a76","a77","a78","a79",
    "a80","a81","a82","a83","a84","a85","a86","a87","a88","a89","a90","a91","a92","a93","a94","a95",
    "a96","a97","a98","a99","a100","a101","a102","a103","a104","a105","a106","a107","a108","a109","a110","a111",
    "a112","a113","a114","a115","a116","a117","a118","a119","a120","a121","a122","a123","a124","a125","a126","a127",
    "a128","a129","a130","a131","a132","a133","a134","a135","a136","a137","a138","a139","a140","a141","a142","a143",
    "a144","a145","a146","a147","a148","a149","a150","a151","a152","a153","a154","a155","a156","a157","a158","a159",
    "a160","a161","a162","a163","a164","a165","a166","a167","a168","a169","a170","a171","a172","a173","a174","a175",
    "a176","a177","a178","a179","a180","a181","a182","a183","a184","a185","a186","a187","a188","a189","a190","a191",
    "a192","a193","a194","a195","a196","a197","a198","a199","a200","a201","a202","a203","a204","a205","a206","a207",
    "a208","a209","a210","a211","a212","a213","a214","a215","a216","a217","a218","a219","a220","a221","a222","a223",
    "a224","a225","a226","a227","a228","a229","a230","a231","a232","a233","a234","a235","a236","a237","a238","a239",
    "a240","a241","a242","a243","a244","a245","a246","a247","a248","a249","a250","a251","a252","a253","a254","a255");

  // AGPR map: gate g in {0:i,1:f,2:g,3:o} -> a[64g + kk], kk in [0,64).
  const float4* Wg0 = (const float4*)(wf + OF_WHH + (size_t)(j      ) * NH + 64 * kh);
  const float4* Wg1 = (const float4*)(wf + OF_WHH + (size_t)(j + 128) * NH + 64 * kh);
  const float4* Wg2 = (const float4*)(wf + OF_WHH + (size_t)(j + 256) * NH + 64 * kh);
  const float4* Wg3 = (const float4*)(wf + OF_WHH + (size_t)(j + 384) * NH + 64 * kh);

#define WRQ(PTR, Q, K0, K1, K2, K3) { float4 v = (PTR)[Q]; \
  asm volatile("v_accvgpr_write_b32 a" #K0 ", %0" :: "v"(v.x)); \
  asm volatile("v_accvgpr_write_b32 a" #K1 ", %0" :: "v"(v.y)); \
  asm volatile("v_accvgpr_write_b32 a" #K2 ", %0" :: "v"(v.z)); \
  asm volatile("v_accvgpr_write_b32 a" #K3 ", %0" :: "v"(v.w)); }
  WRQ(Wg0, 0,   0,  1,  2,  3) WRQ(Wg0, 1,   4,  5,  6,  7)
  WRQ(Wg0, 2,   8,  9, 10, 11) WRQ(Wg0, 3,  12, 13, 14, 15)
  WRQ(Wg0, 4,  16, 17, 18, 19) WRQ(Wg0, 5,  20, 21, 22, 23)
  WRQ(Wg0, 6,  24, 25, 26, 27) WRQ(Wg0, 7,  28, 29, 30, 31)
  WRQ(Wg0, 8,  32, 33, 34, 35) WRQ(Wg0, 9,  36, 37, 38, 39)
  WRQ(Wg0, 10, 40, 41, 42, 43) WRQ(Wg0, 11, 44, 45, 46, 47)
  WRQ(Wg0, 12, 48, 49, 50, 51) WRQ(Wg0, 13, 52, 53, 54, 55)
  WRQ(Wg0, 14, 56, 57, 58, 59) WRQ(Wg0, 15, 60, 61, 62, 63)
  WRQ(Wg1, 0,  64, 65, 66, 67) WRQ(Wg1, 1,  68, 69, 70, 71)
  WRQ(Wg1, 2,  72, 73, 74, 75) WRQ(Wg1, 3,  76, 77, 78, 79)
  WRQ(Wg1, 4,  80, 81, 82, 83) WRQ(Wg1, 5,  84, 85, 86, 87)
  WRQ(Wg1, 6,  88, 89, 90, 91) WRQ(Wg1, 7,  92, 93, 94, 95)
  WRQ(Wg1, 8,  96, 97, 98, 99) WRQ(Wg1, 9, 100,101,102,103)
  WRQ(Wg1, 10,104,105,106,107) WRQ(Wg1, 11,108,109,110,111)
  WRQ(Wg1, 12,112,113,114,115) WRQ(Wg1, 13,116,117,118,119)
  WRQ(Wg1, 14,120,121,122,123) WRQ(Wg1, 15,124,125,126,127)
  WRQ(Wg2, 0, 128,129,130,131) WRQ(Wg2, 1, 132,133,134,135)
  WRQ(Wg2, 2, 136,137,138,139) WRQ(Wg2, 3, 140,141,142,143)
  WRQ(Wg2, 4, 144,145,146,147) WRQ(Wg2, 5, 148,149,150,151)
  WRQ(Wg2, 6, 152,153,154,155) WRQ(Wg2, 7, 156,157,158,159)
  WRQ(Wg2, 8, 160,161,162,163) WRQ(Wg2, 9, 164,165,166,167)
  WRQ(Wg2, 10,168,169,170,171) WRQ(Wg2, 11,172,173,174,175)
  WRQ(Wg2, 12,176,177,178,179) WRQ(Wg2, 13,180,181,182,183)
  WRQ(Wg2, 14,184,185,186,187) WRQ(Wg2, 15,188,189,190,191)
  WRQ(Wg3, 0, 192,193,194,195) WRQ(Wg3, 1, 196,197,198,199)
  WRQ(Wg3, 2, 200,201,202,203) WRQ(Wg3, 3, 204,205,206,207)
  WRQ(Wg3, 4, 208,209,210,211) WRQ(Wg3, 5, 212,213,214,215)
  WRQ(Wg3, 6, 216,217,218,219) WRQ(Wg3, 7, 220,221,222,223)
  WRQ(Wg3, 8, 224,225,226,227) WRQ(Wg3, 9, 228,229,230,231)
  WRQ(Wg3, 10,232,233,234,235) WRQ(Wg3, 11,236,237,238,239)
  WRQ(Wg3, 12,240,241,242,243) WRQ(Wg3, 13,244,245,246,247)
  WRQ(Wg3, 14,248,249,250,251) WRQ(Wg3, 15,252,253,254,255)
#undef WRQ

#define FMQ(HV, A0,A1,A2,A3, B0,B1,B2,B3, C0,C1,C2,C3, D0,D1,D2,D3) { \
  float ta, tb, tc, td; \
  asm volatile("v_accvgpr_read_b32 %0, a" #A0 : "=v"(ta)); \
  asm volatile("v_accvgpr_read_b32 %0, a" #B0 : "=v"(tb)); \
  asm volatile("v_accvgpr_read_b32 %0, a" #C0 : "=v"(tc)); \
  asm volatile("v_accvgpr_read_b32 %0, a" #D0 : "=v"(td)); \
  ac0 += ta * HV.x; ac1 += tb * HV.x; ac2 += tc * HV.x; ac3 += td * HV.x; \
  asm volatile("v_accvgpr_read_b32 %0, a" #A1 : "=v"(ta)); \
  asm volatile("v_accvgpr_read_b32 %0, a" #B1 : "=v"(tb)); \
  asm volatile("v_accvgpr_read_b32 %0, a" #C1 : "=v"(tc)); \
  asm volatile("v_accvgpr_read_b32 %0, a" #D1 : "=v"(td)); \
  ac0 += ta * HV.y; ac1 += tb * HV.y; ac2 += tc * HV.y; ac3 += td * HV.y; \
  asm volatile("v_accvgpr_read_b32 %0, a" #A2 : "=v"(ta)); \
  asm volatile("v_accvgpr_read_b32 %0, a" #B2 : "=v"(tb)); \
  asm volatile("v_accvgpr_read_b32 %0, a" #C2 : "=v"(tc)); \
  asm volatile("v_accvgpr_read_b32 %0, a" #D2 : "=v"(td)); \
  ac0 += ta * HV.z; ac1 += tb * HV.z; ac2 += tc * HV.z; ac3 += td * HV.z; \
  asm volatile("v_accvgpr_read_b32 %0, a" #A3 : "=v"(ta)); \
  asm volatile("v_accvgpr_read_b32 %0, a" #B3 : "=v"(tb)); \
  asm volatile("v_accvgpr_read_b32 %0, a" #C3 : "=v"(tc)); \
  asm volatile("v_accvgpr_read_b32 %0, a" #D3 : "=v"(td)); \
  ac0 += ta * HV.w; ac1 += tb * HV.w; ac2 += tc * HV.w; ac3 += td * HV.w; }

  float c = 0.f;
  if (tid < NH) h_sh[tid] = 0.f;
  __syncthreads();
  float4 gnext = make_float4(0.f, 0.f, 0.f, 0.f);
  if (kh == 0) gnext = *(const float4*)(G1 + (size_t)0 * 512 + j * 4);   // prefetch t=0
#pragma unroll 1
  for (int t = 0; t < NL; ++t) {
    float4 gcur = gnext;
    if (kh == 0 && t + 1 < NL)
      gnext = *(const float4*)(G1 + (size_t)(t + 1) * 512 + j * 4);
    const float4* h4 = (const float4*)(h_sh + (kh << 6));
    // preload h (wave-uniform broadcast) into named regs BEFORE the asm
    // region — C loads cannot sink past the volatile asm, so load them all.
    float4 hv0 = h4[0],  hv1 = h4[1],  hv2 = h4[2],  hv3 = h4[3];
    float4 hv4 = h4[4],  hv5 = h4[5],  hv6 = h4[6],  hv7 = h4[7];
    float4 hv8 = h4[8],  hv9 = h4[9],  hv10 = h4[10], hv11 = h4[11];
    float4 hv12 = h4[12], hv13 = h4[13], hv14 = h4[14], hv15 = h4[15];
    float ac0 = 0.f, ac1 = 0.f, ac2 = 0.f, ac3 = 0.f;
    FMQ(hv0,   0,  1,  2,  3,  64, 65, 66, 67, 128,129,130,131, 192,193,194,195)
    FMQ(hv1,   4,  5,  6,  7,  68, 69, 70, 71, 132,133,134,135, 196,197,198,199)
    FMQ(hv2,   8,  9, 10, 11,  72, 73, 74, 75, 136,137,138,139, 200,201,202,203)
    FMQ(hv3,  12, 13, 14, 15,  76, 77, 78, 79, 140,141,142,143, 204,205,206,207)
    FMQ(hv4,  16, 17, 18, 19,  80, 81, 82, 83, 144,145,146,147, 208,209,210,211)
    FMQ(hv5,  20, 21, 22, 23,  84, 85, 86, 87, 148,149,150,151, 212,213,214,215)
    FMQ(hv6,  24, 25, 26, 27,  88, 89, 90, 91, 152,153,154,155, 216,217,218,219)
    FMQ(hv7,  28, 29, 30, 31,  92, 93, 94, 95, 156,157,158,159, 220,221,222,223)
    FMQ(hv8,  32, 33, 34, 35,  96, 97, 98, 99, 160,161,162,163, 224,225,226,227)
    FMQ(hv9,  36, 37, 38, 39, 100,101,102,103, 164,165,166,167, 228,229,230,231)
    FMQ(hv10, 40, 41, 42, 43, 104,105,106,107, 168,169,170,171, 232,233,234,235)
    FMQ(hv11, 44, 45, 46, 47, 108,109,110,111, 172,173,174,175, 236,237,238,239)
    FMQ(hv12, 48, 49, 50, 51, 112,113,114,115, 176,177,178,179, 240,241,242,243)
    FMQ(hv13, 52, 53, 54, 55, 116,117,118,119, 180,181,182,183, 244,245,246,247)
    FMQ(hv14, 56, 57, 58, 59, 120,121,122,123, 184,185,186,187, 248,249,250,251)
    FMQ(hv15, 60, 61, 62, 63, 124,125,126,127, 188,189,190,191, 252,253,254,255)
    float4 pv;
    pv.x = ac0; pv.y = ac1; pv.z = ac2; pv.w = ac3;
    *(float4*)part_sh[tid] = pv;
    __syncthreads();
    if (kh == 0) {                           // thread j owns h-row j; gates i,f,g,o
      float4 po = *(const float4*)part_sh[tid + 128];   // partner k-half
      float iv = pv.x + po.x + gcur.x;
      float fv = pv.y + po.y + gcur.y;
      float gv = pv.z + po.z + gcur.z;
      float ov = pv.w + po.w + gcur.w;
      float si = 1.f / (1.f + __expf(-iv));
      float sf = 1.f / (1.f + __expf(-fv));
      float tg = 1.f - 2.f / (__expf(2.f * gv) + 1.f);
      float so = 1.f / (1.f + __expf(-ov));
      c = sf * c + si * tg;
      float hh = so * (1.f - 2.f / (__expf(2.f * c) + 1.f));
      h_sh[j] = hh;
      hidden[(size_t)(NL - 1 + t) * NH + j] = hh;   // leaf node L-1+t
    }
    __syncthreads();
  }
#undef FMQ
}

// ------------------------------------------------ one tree level: pair -> parent hidden
__global__ void p2h_kernel(const float* __restrict__ wf, float* __restrict__ hidden, int base) {
  int node = base + blockIdx.x;
  int j = threadIdx.x;                       // 128
  __shared__ __attribute__((aligned(16))) float pr[2 * NH];
  const float* hl = hidden + (size_t)(2 * node + 1) * NH;  // children contiguous
  pr[j] = hl[j];
  pr[j + NH] = hl[j + NH];
  __syncthreads();
  float acc = wf[OF_BP2H + j];
  const float4* W4 = (const float4*)(wf + OF_WP2H + (size_t)j * 2 * NH);
  const float4* p4 = (const float4*)pr;
#pragma unroll 16
  for (int q = 0; q < 64; ++q) {
    float4 u = W4[q], x = p4[q];
    acc += u.x * x.x + u.y * x.y + u.z * x.z + u.w * x.w;
  }
  hidden[(size_t)node * NH + j] = acc;
}

// ------------------------------------------------ unary = hidden@W_uni^T + b; zero f2n[0]
__global__ void unary_kernel(const float* __restrict__ wf, const float* __restrict__ hidden,
                             float* __restrict__ unary, float* __restrict__ f2n) {
  int node = blockIdx.x;
  int ct = threadIdx.x;                      // 64
  __shared__ __attribute__((aligned(16))) float hs[NH];
  hs[ct] = hidden[(size_t)node * NH + ct];
  hs[ct + 64] = hidden[(size_t)node * NH + 64 + ct];
  __syncthreads();
  float acc = wf[OF_BUNI + ct];
  const float4* W4 = (const float4*)(wf + OF_WUNI + (size_t)ct * NH);
  const float4* h4 = (const float4*)hs;
#pragma unroll
  for (int q = 0; q < 32; ++q) {
    float4 u = W4[q], x = h4[q];
    acc += u.x * x.x + u.y * x.y + u.z * x.z + u.w * x.w;
  }
  unary[(size_t)node * NT + ct] = acc;
  if (node == 0) f2n[ct] = 0.f;              // root gets no top-factor message
}

// ------------------------------------------------ edge_fac GEMM: [8192,256]x[256,4096]
__global__ __launch_bounds__(256) void edge_kernel(const float* __restrict__ hidden,
                                                   const float* __restrict__ wf,
                                                   float* __restrict__ edge) {
  __shared__ __attribute__((aligned(16))) float As[32][132];  // [k][m]
  __shared__ __attribute__((aligned(16))) float Bs[32][132];  // [k][n]
  const int tid = threadIdx.x;
  const int nb = blockIdx.x;                 // 0..31 (N tile of 128)
  const int mb = blockIdx.y;                 // 0..63 (M tile of 128)
  const int tm = tid >> 4, tn = tid & 15;    // 16x16 threads, 8x8 micro (split 4+4)
  float acc[8][8];
#pragma unroll
  for (int i = 0; i < 8; ++i)
#pragma unroll
    for (int j = 0; j < 8; ++j) acc[i][j] = 0.f;
  const int sr = tid >> 1;                   // staging row 0..127
  const int sq = tid & 1;                    // which 16-k half
  for (int ch = 0; ch < 8; ++ch) {           // K chunks of 32
    {                                        // stage A
      int gm = mb * 128 + sr;
      const float* srcA = (ch < 4) ? hidden + (size_t)(gm >> 1) * NH + ch * 32
                                   : hidden + (size_t)(gm + 1) * NH + (ch - 4) * 32;
      bool ok = (gm < NNODE - 1);
#pragma unroll
      for (int i = 0; i < 4; ++i) {
        int kk = sq * 16 + i * 4;
        float4 v = ok ? *(const float4*)(srcA + kk) : make_float4(0.f, 0.f, 0.f, 0.f);
        As[kk + 0][sr] = v.x; As[kk + 1][sr] = v.y; As[kk + 2][sr] = v.z; As[kk + 3][sr] = v.w;
      }
    }
    {                                        // stage B
      int gn = nb * 128 + sr;                // < 4096 always
      const float* srcB = wf + OF_WEDGE + (size_t)gn * NE + ch * 32;
#pragma unroll
      for (int i = 0; i < 4; ++i) {
        int kk = sq * 16 + i * 4;
        float4 v = *(const float4*)(srcB + kk);
        Bs[kk + 0][sr] = v.x; Bs[kk + 1][sr] = v.y; Bs[kk + 2][sr] = v.z; Bs[kk + 3][sr] = v.w;
      }
    }
    __syncthreads();
#pragma unroll 8
    for (int kk = 0; kk < 32; ++kk) {
      float a[8], b[8];
      *(float4*)(a)     = *(const float4*)&As[kk][tm * 4];
      *(float4*)(a + 4) = *(const float4*)&As[kk][64 + tm * 4];
      *(float4*)(b)     = *(const float4*)&Bs[kk][tn * 4];
      *(float4*)(b + 4) = *(const float4*)&Bs[kk][64 + tn * 4];
#pragma unroll
      for (int i = 0; i < 8; ++i)
#pragma unroll
        for (int j = 0; j < 8; ++j) acc[i][j] += a[i] * b[j];
    }
    __syncthreads();
  }
  float bias[8];
#pragma unroll
  for (int j = 0; j < 8; ++j)
    bias[j] = wf[OF_BEDGE + nb * 128 + (j >> 2) * 64 + tn * 4 + (j & 3)];
#pragma unroll
  for (int i = 0; i < 8; ++i) {
    int gm = mb * 128 + (i >> 2) * 64 + tm * 4 + (i & 3);
    if (gm < NNODE - 1) {
      float* row = edge + (size_t)gm * 4096 + nb * 128;
      float4 o0, o1;
      o0.x = acc[i][0] + bias[0]; o0.y = acc[i][1] + bias[1];
      o0.z = acc[i][2] + bias[2]; o0.w = acc[i][3] + bias[3];
      o1.x = acc[i][4] + bias[4]; o1.y = acc[i][5] + bias[5];
      o1.z = acc[i][6] + bias[6]; o1.w = acc[i][7] + bias[7];
      *(float4*)(row + tn * 4) = o0;
      *(float4*)(row + 64 + tn * 4) = o1;
    }
  }
}

// ------------------------------------------------ upward level
__global__ void up_kernel(const float* __restrict__ unary, const float* __restrict__ edge,
                          float* __restrict__ v2f, float* __restrict__ f2p,
                          int base, int depth) {
  int node = base + blockIdx.x;
  int tid = threadIdx.x;                     // 64; tid = p (parent tag)
  __shared__ __attribute__((aligned(16))) float vs[NT];
  float vv = unary[(size_t)node * NT + tid];
  if (depth < NDEPTH)
    vv += f2p[(size_t)(2 * node + 1) * NT + tid] + f2p[(size_t)(2 * node + 2) * NT + tid];
  v2f[(size_t)node * NT + tid] = vv;
  vs[tid] = vv;
  __syncthreads();
  if (depth == 0) return;
  const float4* E4 = (const float4*)(edge + (size_t)(node - 1) * 4096 + tid * 64);
  const float4* v4 = (const float4*)vs;
  float x[NT];
#pragma unroll
  for (int q = 0; q < 16; ++q) {
    float4 e = E4[q], vq = v4[q];
    x[4 * q + 0] = e.x + vq.x; x[4 * q + 1] = e.y + vq.y;
    x[4 * q + 2] = e.z + vq.z; x[4 * q + 3] = e.w + vq.w;
  }
  float m = x[0];
#pragma unroll
  for (int i = 1; i < NT; ++i) m = fmaxf(m, x[i]);
  float s = 0.f;
#pragma unroll
  for (int i = 0; i < NT; ++i) s += __expf(x[i] - m);
  f2p[(size_t)node * NT + tid] = m + __logf(s);
}

// ------------------------------------------------ downward level
__global__ void down_kernel(const float* __restrict__ unary, const float* __restrict__ edge,
                            const float* __restrict__ f2p, float* __restrict__ f2n,
                            int base) {
  int node = base + blockIdx.x;
  int tid = threadIdx.x;                     // 64; tid = c (child tag)
  int par = (node - 1) >> 1;
  int sib = (node & 1) ? node + 1 : node - 1;
  __shared__ __attribute__((aligned(16))) float us[NT];
  us[tid] = unary[(size_t)par * NT + tid] + f2n[(size_t)par * NT + tid] +
            f2p[(size_t)sib * NT + tid];
  __syncthreads();
  float uu[NT];
  const float4* u4 = (const float4*)us;
#pragma unroll
  for (int q = 0; q < 16; ++q) {
    float4 t4 = u4[q];
    uu[4 * q] = t4.x; uu[4 * q + 1] = t4.y; uu[4 * q + 2] = t4.z; uu[4 * q + 3] = t4.w;
  }
  const float* E = edge + (size_t)(node - 1) * 4096 + tid;
  float x[NT];
#pragma unroll
  for (int p = 0; p < NT; ++p) x[p] = E[(size_t)p * 64] + uu[p];
  float m = x[0];
#pragma unroll
  for (int i = 1; i < NT; ++i) m = fmaxf(m, x[i]);
  float s = 0.f;
#pragma unroll
  for (int i = 0; i < NT; ++i) s += __expf(x[i] - m);
  f2n[(size_t)node * NT + tid] = m + __logf(s);
}

// ------------------------------------------------ beliefs -> postorder -> out (flag dtype)
__global__ void final_kernel(const float* __restrict__ v2f, const float* __restrict__ f2n,
                             const int* __restrict__ flag, void* __restrict__ out) {
  int node = blockIdx.x;
  int tid = threadIdx.x;                     // 64
  unsigned v = (unsigned)node + 1u;
  int d = 31 - __clz((int)v);
  int b0 = 0, S = NNODE;
  for (int b = d - 1; b >= 0; --b) {
    int sz = (S - 1) >> 1;
    if ((v >> b) & 1) b0 += sz;
    S = sz;
  }
  int pos = b0 + S - 1;
  float val = v2f[(size_t)node * NT + tid] + f2n[(size_t)node * NT + tid];
  if ((*flag) > 100) ((float*)out)[(size_t)pos * NT + tid] = val;
  else               ((bf16*)out)[(size_t)pos * NT + tid] = __float2bfloat16(val);
}

// ------------------------------------------------
extern "C" void kernel_launch(void* const* d_in, const int* in_sizes, int n_in,
                              void* d_out, int out_size, void* d_ws, size_t ws_size,
                              hipStream_t stream) {
  (void)in_sizes; (void)n_in; (void)out_size; (void)ws_size;
  const int* tokens = (const int*)d_in[0];

  // workspace layout (floats); ~160.3 MB total
  float* ws     = (float*)d_ws;
  int*   flag   = (int*)ws;                            // [16]
  float* wf     = ws + 16;                             // converted f32 weights
  float* hidden = wf + WF_TOTAL;                       // [8191][128]
  float* G1     = hidden + (size_t)NNODE * NH;         // [4096][512] gate-interleaved
  float* unary  = G1 + (size_t)NL * 512;               // [8191][64]
  float* v2f    = unary + (size_t)NNODE * NT;          // [8191][64]
  float* f2p    = v2f + (size_t)NNODE * NT;            // [8191][64]
  float* f2n    = f2p + (size_t)NNODE * NT;            // [8191][64]
  float* edge   = f2n + (size_t)NNODE * NT;            // [8190][4096]

  detect_kernel<<<1, 256, 0, stream>>>(d_in[10], flag);
  convert_kernel<<<(WF_TOTAL + 255) / 256, 256, 0, stream>>>(
      d_in[2], d_in[3], d_in[4], d_in[5], d_in[6], d_in[7],
      d_in[8], d_in[9], d_in[10], d_in[11], flag, wf);
  g1_kernel<<<NL / 8, 512, 0, stream>>>(tokens, d_in[1], flag, wf, G1);
  lstm_kernel<<<1, 256, 0, stream>>>(wf, G1, hidden);
  for (int d = NDEPTH - 1; d >= 0; --d)
    p2h_kernel<<<1 << d, 128, 0, stream>>>(wf, hidden, (1 << d) - 1);
  unary_kernel<<<NNODE, 64, 0, stream>>>(wf, hidden, unary, f2n);
  edge_kernel<<<dim3(32, 64), 256, 0, stream>>>(hidden, wf, edge);
  for (int d = NDEPTH; d >= 0; --d)
    up_kernel<<<1 << d, 64, 0, stream>>>(unary, edge, v2f, f2p, (1 << d) - 1, d);
  for (int d = 1; d <= NDEPTH; ++d)
    down_kernel<<<1 << d, 64, 0, stream>>>(unary, edge, f2p, f2n, (1 << d) - 1);
  final_kernel<<<NNODE, 64, 0, stream>>>(v2f, f2n, flag, d_out);
}

// Round 6
// 4859.489 us; speedup vs baseline: 1.2375x; 1.2375x over previous
//
#include <hip/hip_runtime.h>
#include <hip/hip_bf16.h>

typedef __hip_bfloat16 bf16;
typedef float fx2 __attribute__((ext_vector_type(2)));

#define NL 4096      // L leaves
#define NH 128       // H hidden
#define NE 256       // E embed
#define NT 64        // T tags
#define NNODE 8191   // N = 2L-1
#define NDEPTH 12    // D = log2(L)

// converted f32 weights, offsets into wf[] (floats)
#define OF_WIH   0
#define OF_WHH   131072
#define OF_BIH   196608
#define OF_BHH   197120
#define OF_WP2H  197632
#define OF_BP2H  230400
#define OF_WUNI  230528
#define OF_BUNI  238720
#define OF_WEDGE 238784
#define OF_BEDGE 1287360
#define WF_TOTAL 1291456

__device__ __forceinline__ float b2f(bf16 x) { return __bfloat162float(x); }

// ------------------------------------------------ dtype detection
__global__ void detect_kernel(const void* __restrict__ wedge_raw, int* __restrict__ flag) {
  __shared__ int cnt_sh[256];
  const unsigned short* p = (const unsigned short*)wedge_raw;
  int c = 0;
  for (int i = threadIdx.x; i < 32768; i += 256) {
    float v = __uint_as_float(((unsigned)p[2 * i]) << 16);
    if (fabsf(v) > 4.f) c++;
  }
  cnt_sh[threadIdx.x] = c;
  __syncthreads();
  for (int s = 128; s > 0; s >>= 1) {
    if (threadIdx.x < s) cnt_sh[threadIdx.x] += cnt_sh[threadIdx.x + s];
    __syncthreads();
  }
  if (threadIdx.x == 0) *flag = cnt_sh[0];   // >100 => inputs are f32
}

// ------------------------------------------------ convert all weights -> f32 in ws
__global__ void convert_kernel(const void* s0, const void* s1, const void* s2, const void* s3,
                               const void* s4, const void* s5, const void* s6, const void* s7,
                               const void* s8, const void* s9,
                               const int* __restrict__ flag, float* __restrict__ wf) {
  int i = blockIdx.x * 256 + threadIdx.x;
  if (i >= WF_TOTAL) return;
  const void* src; int local;
  if      (i < OF_WHH)   { src = s0; local = i; }
  else if (i < OF_BIH)   { src = s1; local = i - OF_WHH; }
  else if (i < OF_BHH)   { src = s2; local = i - OF_BIH; }
  else if (i < OF_WP2H)  { src = s3; local = i - OF_BHH; }
  else if (i < OF_BP2H)  { src = s4; local = i - OF_WP2H; }
  else if (i < OF_WUNI)  { src = s5; local = i - OF_BP2H; }
  else if (i < OF_BUNI)  { src = s6; local = i - OF_WUNI; }
  else if (i < OF_WEDGE) { src = s7; local = i - OF_BUNI; }
  else if (i < OF_BEDGE) { src = s8; local = i - OF_WEDGE; }
  else                   { src = s9; local = i - OF_BEDGE; }
  bool isf32 = (*flag) > 100;
  wf[i] = isf32 ? ((const float*)src)[local] : b2f(((const bf16*)src)[local]);
}

// ------------------------------------------------ G1 = emb[tok]@W_ih^T + b_ih + b_hh
__global__ __launch_bounds__(512) void g1_kernel(const int* __restrict__ tokens,
                                                 const void* __restrict__ emb_raw,
                                                 const int* __restrict__ flag,
                                                 const float* __restrict__ wf,
                                                 float* __restrict__ G1) {
  __shared__ __attribute__((aligned(16))) float xs[8 * NE];
  const bool isf32 = (*flag) > 100;
  const int t0 = blockIdx.x * 8;
  for (int q = threadIdx.x; q < 8 * NE; q += 512) {
    int tok = q >> 8, e = q & 255;
    size_t off = (size_t)tokens[t0 + tok] * NE + e;
    xs[q] = isf32 ? ((const float*)emb_raw)[off] : b2f(((const bf16*)emb_raw)[off]);
  }
  __syncthreads();
  const int r = threadIdx.x;                 // gate row 0..511
  const float bias = wf[OF_BIH + r] + wf[OF_BHH + r];
  float acc[8];
#pragma unroll
  for (int k = 0; k < 8; ++k) acc[k] = bias;
  const float4* W4 = (const float4*)(wf + OF_WIH + (size_t)r * NE);
#pragma unroll 8
  for (int j = 0; j < 64; ++j) {
    float4 wv = W4[j];
#pragma unroll
    for (int tok = 0; tok < 8; ++tok) {
      float4 xv = ((const float4*)(xs + tok * NE))[j];   // wave-uniform broadcast
      acc[tok] += wv.x * xv.x + wv.y * xv.y + wv.z * xv.z + wv.w * xv.w;
    }
  }
#pragma unroll
  for (int tok = 0; tok < 8; ++tok) G1[(size_t)(t0 + tok) * 512 + r] = acc[tok];
}

// ------------------------------------------------ sequential LSTM, 1 block, 512 threads
// Delivery-split design. Measured facts (rounds 0-5): the step cost is the
// 256 KB/step W_hh delivery from L2 at ~125 B/cyc (~1940 cyc); registers
// cannot hold the weights (allocator remats/spills, 5 variants), AGPR
// residency costs 2x issue (R5). LDS (~128 B/cyc) and L2 (~125 B/cyc) are
// SEPARATE pipes (lgkmcnt vs vmcnt): put half of W_hh (k<64, 128 KB) in LDS
// once, stream the other half (k>=64, 128 KB) from L2 per step exactly as
// the fastest prior version did. Both streams run concurrently =>
// delivery ~1000-1150 cyc/step instead of 1940. h reads are same-address
// wave broadcasts (hardware-free, not a BW term).
// W_lds layout [kq][r]: lane r reads 16B at stride 16B across lanes =
// the standard full-bandwidth LDS pattern (no conflicts).
__global__ __launch_bounds__(512) void lstm_kernel(const float* __restrict__ wf,
                                                   const float* __restrict__ G1,
                                                   float* __restrict__ hidden) {
  const int r = threadIdx.x;                 // gate row 0..511
  __shared__ __attribute__((aligned(16))) float4 Wl[16 * 512];   // 128 KB: [kq][r], k<64
  __shared__ __attribute__((aligned(16))) float h_sh[NH];
  __shared__ float g_sh[512];

  const float4* Wrow = (const float4*)(wf + OF_WHH + (size_t)r * NH);   // row r, 32 quads
  // stage k<64 (quads 0..15) into LDS
#pragma unroll
  for (int kq = 0; kq < 16; ++kq) Wl[kq * 512 + r] = Wrow[kq];

  float c = 0.f;
  if (r < NH) h_sh[r] = 0.f;
  __syncthreads();
  float gnext = G1[r];                       // prefetch t=0
  for (int t = 0; t < NL; ++t) {
    float gcur = gnext;
    if (t + 1 < NL) gnext = G1[(size_t)(t + 1) * 512 + r];
    const float4* h4 = (const float4*)h_sh;
    fx2 a0 = {0.f, 0.f}, a1 = {0.f, 0.f}, a2 = {0.f, 0.f}, a3 = {0.f, 0.f};
    // ---- k in [64,128): stream from L2 (vmcnt pipe) ----
#pragma unroll
    for (int kq = 0; kq < 16; ++kq) {
      float4 wq = Wrow[16 + kq];             // loop-invariant addr; compiler re-loads (L2-resident)
      float4 hq = h4[16 + kq];               // broadcast
      fx2 w0, w1, e0, e1;
      w0.x = wq.x; w0.y = wq.y; w1.x = wq.z; w1.y = wq.w;
      e0.x = hq.x; e0.y = hq.y; e1.x = hq.z; e1.y = hq.w;
      a0 += w0 * e0;
      a1 += w1 * e1;
    }
    // ---- k in [0,64): from LDS (lgkmcnt pipe) ----
#pragma unroll
    for (int kq = 0; kq < 16; ++kq) {
      float4 wq = Wl[kq * 512 + r];          // per-lane ds_read_b128, stride 16B
      float4 hq = h4[kq];                    // broadcast
      fx2 w0, w1, e0, e1;
      w0.x = wq.x; w0.y = wq.y; w1.x = wq.z; w1.y = wq.w;
      e0.x = hq.x; e0.y = hq.y; e1.x = hq.z; e1.y = hq.w;
      a2 += w0 * e0;
      a3 += w1 * e1;
    }
    g_sh[r] = gcur + (a0.x + a0.y) + (a1.x + a1.y) + (a2.x + a2.y) + (a3.x + a3.y);
    __syncthreads();
    if (r < NH) {                            // gate order i,f,g,o
      float iv = g_sh[r], fv = g_sh[r + 128], gv = g_sh[r + 256], ov = g_sh[r + 384];
      float si = 1.f / (1.f + __expf(-iv));
      float sf = 1.f / (1.f + __expf(-fv));
      float tg = 1.f - 2.f / (__expf(2.f * gv) + 1.f);
      float so = 1.f / (1.f + __expf(-ov));
      c = sf * c + si * tg;
      float hh = so * (1.f - 2.f / (__expf(2.f * c) + 1.f));
      h_sh[r] = hh;
      hidden[(size_t)(NL - 1 + t) * NH + r] = hh;   // leaf node L-1+t
    }
    __syncthreads();
  }
}

// ------------------------------------------------ one tree level: pair -> parent hidden
__global__ void p2h_kernel(const float* __restrict__ wf, float* __restrict__ hidden, int base) {
  int node = base + blockIdx.x;
  int j = threadIdx.x;                       // 128
  __shared__ __attribute__((aligned(16))) float pr[2 * NH];
  const float* hl = hidden + (size_t)(2 * node + 1) * NH;  // children contiguous
  pr[j] = hl[j];
  pr[j + NH] = hl[j + NH];
  __syncthreads();
  float acc = wf[OF_BP2H + j];
  const float4* W4 = (const float4*)(wf + OF_WP2H + (size_t)j * 2 * NH);
  const float4* p4 = (const float4*)pr;
#pragma unroll 16
  for (int q = 0; q < 64; ++q) {
    float4 u = W4[q], x = p4[q];
    acc += u.x * x.x + u.y * x.y + u.z * x.z + u.w * x.w;
  }
  hidden[(size_t)node * NH + j] = acc;
}

// ------------------------------------------------ unary = hidden@W_uni^T + b; zero f2n[0]
__global__ void unary_kernel(const float* __restrict__ wf, const float* __restrict__ hidden,
                             float* __restrict__ unary, float* __restrict__ f2n) {
  int node = blockIdx.x;
  int ct = threadIdx.x;                      // 64
  __shared__ __attribute__((aligned(16))) float hs[NH];
  hs[ct] = hidden[(size_t)node * NH + ct];
  hs[ct + 64] = hidden[(size_t)node * NH + 64 + ct];
  __syncthreads();
  float acc = wf[OF_BUNI + ct];
  const float4* W4 = (const float4*)(wf + OF_WUNI + (size_t)ct * NH);
  const float4* h4 = (const float4*)hs;
#pragma unroll
  for (int q = 0; q < 32; ++q) {
    float4 u = W4[q], x = h4[q];
    acc += u.x * x.x + u.y * x.y + u.z * x.z + u.w * x.w;
  }
  unary[(size_t)node * NT + ct] = acc;
  if (node == 0) f2n[ct] = 0.f;              // root gets no top-factor message
}

// ------------------------------------------------ edge_fac GEMM: [8192,256]x[256,4096]
__global__ __launch_bounds__(256) void edge_kernel(const float* __restrict__ hidden,
                                                   const float* __restrict__ wf,
                                                   float* __restrict__ edge) {
  __shared__ __attribute__((aligned(16))) float As[32][132];  // [k][m]
  __shared__ __attribute__((aligned(16))) float Bs[32][132];  // [k][n]
  const int tid = threadIdx.x;
  const int nb = blockIdx.x;                 // 0..31 (N tile of 128)
  const int mb = blockIdx.y;                 // 0..63 (M tile of 128)
  const int tm = tid >> 4, tn = tid & 15;    // 16x16 threads, 8x8 micro (split 4+4)
  float acc[8][8];
#pragma unroll
  for (int i = 0; i < 8; ++i)
#pragma unroll
    for (int j = 0; j < 8; ++j) acc[i][j] = 0.f;
  const int sr = tid >> 1;                   // staging row 0..127
  const int sq = tid & 1;                    // which 16-k half
  for (int ch = 0; ch < 8; ++ch) {           // K chunks of 32
    {                                        // stage A
      int gm = mb * 128 + sr;
      const float* srcA = (ch < 4) ? hidden + (size_t)(gm >> 1) * NH + ch * 32
                                   : hidden + (size_t)(gm + 1) * NH + (ch - 4) * 32;
      bool ok = (gm < NNODE - 1);
#pragma unroll
      for (int i = 0; i < 4; ++i) {
        int kk = sq * 16 + i * 4;
        float4 v = ok ? *(const float4*)(srcA + kk) : make_float4(0.f, 0.f, 0.f, 0.f);
        As[kk + 0][sr] = v.x; As[kk + 1][sr] = v.y; As[kk + 2][sr] = v.z; As[kk + 3][sr] = v.w;
      }
    }
    {                                        // stage B
      int gn = nb * 128 + sr;                // < 4096 always
      const float* srcB = wf + OF_WEDGE + (size_t)gn * NE + ch * 32;
#pragma unroll
      for (int i = 0; i < 4; ++i) {
        int kk = sq * 16 + i * 4;
        float4 v = *(const float4*)(srcB + kk);
        Bs[kk + 0][sr] = v.x; Bs[kk + 1][sr] = v.y; Bs[kk + 2][sr] = v.z; Bs[kk + 3][sr] = v.w;
      }
    }
    __syncthreads();
#pragma unroll 8
    for (int kk = 0; kk < 32; ++kk) {
      float a[8], b[8];
      *(float4*)(a)     = *(const float4*)&As[kk][tm * 4];
      *(float4*)(a + 4) = *(const float4*)&As[kk][64 + tm * 4];
      *(float4*)(b)     = *(const float4*)&Bs[kk][tn * 4];
      *(float4*)(b + 4) = *(const float4*)&Bs[kk][64 + tn * 4];
#pragma unroll
      for (int i = 0; i < 8; ++i)
#pragma unroll
        for (int j = 0; j < 8; ++j) acc[i][j] += a[i] * b[j];
    }
    __syncthreads();
  }
  float bias[8];
#pragma unroll
  for (int j = 0; j < 8; ++j)
    bias[j] = wf[OF_BEDGE + nb * 128 + (j >> 2) * 64 + tn * 4 + (j & 3)];
#pragma unroll
  for (int i = 0; i < 8; ++i) {
    int gm = mb * 128 + (i >> 2) * 64 + tm * 4 + (i & 3);
    if (gm < NNODE - 1) {
      float* row = edge + (size_t)gm * 4096 + nb * 128;
      float4 o0, o1;
      o0.x = acc[i][0] + bias[0]; o0.y = acc[i][1] + bias[1];
      o0.z = acc[i][2] + bias[2]; o0.w = acc[i][3] + bias[3];
      o1.x = acc[i][4] + bias[4]; o1.y = acc[i][5] + bias[5];
      o1.z = acc[i][6] + bias[6]; o1.w = acc[i][7] + bias[7];
      *(float4*)(row + tn * 4) = o0;
      *(float4*)(row + 64 + tn * 4) = o1;
    }
  }
}

// ------------------------------------------------ upward level
__global__ void up_kernel(const float* __restrict__ unary, const float* __restrict__ edge,
                          float* __restrict__ v2f, float* __restrict__ f2p,
                          int base, int depth) {
  int node = base + blockIdx.x;
  int tid = threadIdx.x;                     // 64; tid = p (parent tag)
  __shared__ __attribute__((aligned(16))) float vs[NT];
  float vv = unary[(size_t)node * NT + tid];
  if (depth < NDEPTH)
    vv += f2p[(size_t)(2 * node + 1) * NT + tid] + f2p[(size_t)(2 * node + 2) * NT + tid];
  v2f[(size_t)node * NT + tid] = vv;
  vs[tid] = vv;
  __syncthreads();
  if (depth == 0) return;
  const float4* E4 = (const float4*)(edge + (size_t)(node - 1) * 4096 + tid * 64);
  const float4* v4 = (const float4*)vs;
  float x[NT];
#pragma unroll
  for (int q = 0; q < 16; ++q) {
    float4 e = E4[q], vq = v4[q];
    x[4 * q + 0] = e.x + vq.x; x[4 * q + 1] = e.y + vq.y;
    x[4 * q + 2] = e.z + vq.z; x[4 * q + 3] = e.w + vq.w;
  }
  float m = x[0];
#pragma unroll
  for (int i = 1; i < NT; ++i) m = fmaxf(m, x[i]);
  float s = 0.f;
#pragma unroll
  for (int i = 0; i < NT; ++i) s += __expf(x[i] - m);
  f2p[(size_t)node * NT + tid] = m + __logf(s);
}

// ------------------------------------------------ downward level
__global__ void down_kernel(const float* __restrict__ unary, const float* __restrict__ edge,
                            const float* __restrict__ f2p, float* __restrict__ f2n,
                            int base) {
  int node = base + blockIdx.x;
  int tid = threadIdx.x;                     // 64; tid = c (child tag)
  int par = (node - 1) >> 1;
  int sib = (node & 1) ? node + 1 : node - 1;
  __shared__ __attribute__((aligned(16))) float us[NT];
  us[tid] = unary[(size_t)par * NT + tid] + f2n[(size_t)par * NT + tid] +
            f2p[(size_t)sib * NT + tid];
  __syncthreads();
  float uu[NT];
  const float4* u4 = (const float4*)us;
#pragma unroll
  for (int q = 0; q < 16; ++q) {
    float4 t4 = u4[q];
    uu[4 * q] = t4.x; uu[4 * q + 1] = t4.y; uu[4 * q + 2] = t4.z; uu[4 * q + 3] = t4.w;
  }
  const float* E = edge + (size_t)(node - 1) * 4096 + tid;
  float x[NT];
#pragma unroll
  for (int p = 0; p < NT; ++p) x[p] = E[(size_t)p * 64] + uu[p];
  float m = x[0];
#pragma unroll
  for (int i = 1; i < NT; ++i) m = fmaxf(m, x[i]);
  float s = 0.f;
#pragma unroll
  for (int i = 0; i < NT; ++i) s += __expf(x[i] - m);
  f2n[(size_t)node * NT + tid] = m + __logf(s);
}

// ------------------------------------------------ beliefs -> postorder -> out (flag dtype)
__global__ void final_kernel(const float* __restrict__ v2f, const float* __restrict__ f2n,
                             const int* __restrict__ flag, void* __restrict__ out) {
  int node = blockIdx.x;
  int tid = threadIdx.x;                     // 64
  unsigned v = (unsigned)node + 1u;
  int d = 31 - __clz((int)v);
  int b0 = 0, S = NNODE;
  for (int b = d - 1; b >= 0; --b) {
    int sz = (S - 1) >> 1;
    if ((v >> b) & 1) b0 += sz;
    S = sz;
  }
  int pos = b0 + S - 1;
  float val = v2f[(size_t)node * NT + tid] + f2n[(size_t)node * NT + tid];
  if ((*flag) > 100) ((float*)out)[(size_t)pos * NT + tid] = val;
  else               ((bf16*)out)[(size_t)pos * NT + tid] = __float2bfloat16(val);
}

// ------------------------------------------------
extern "C" void kernel_launch(void* const* d_in, const int* in_sizes, int n_in,
                              void* d_out, int out_size, void* d_ws, size_t ws_size,
                              hipStream_t stream) {
  (void)in_sizes; (void)n_in; (void)out_size; (void)ws_size;
  const int* tokens = (const int*)d_in[0];

  // workspace layout (floats); ~160.3 MB total
  float* ws     = (float*)d_ws;
  int*   flag   = (int*)ws;                            // [16]
  float* wf     = ws + 16;                             // converted f32 weights
  float* hidden = wf + WF_TOTAL;                       // [8191][128]
  float* G1     = hidden + (size_t)NNODE * NH;         // [4096][512]
  float* unary  = G1 + (size_t)NL * 512;               // [8191][64]
  float* v2f    = unary + (size_t)NNODE * NT;          // [8191][64]
  float* f2p    = v2f + (size_t)NNODE * NT;            // [8191][64]
  float* f2n    = f2p + (size_t)NNODE * NT;            // [8191][64]
  float* edge   = f2n + (size_t)NNODE * NT;            // [8190][4096]

  detect_kernel<<<1, 256, 0, stream>>>(d_in[10], flag);
  convert_kernel<<<(WF_TOTAL + 255) / 256, 256, 0, stream>>>(
      d_in[2], d_in[3], d_in[4], d_in[5], d_in[6], d_in[7],
      d_in[8], d_in[9], d_in[10], d_in[11], flag, wf);
  g1_kernel<<<NL / 8, 512, 0, stream>>>(tokens, d_in[1], flag, wf, G1);
  lstm_kernel<<<1, 512, 0, stream>>>(wf, G1, hidden);
  for (int d = NDEPTH - 1; d >= 0; --d)
    p2h_kernel<<<1 << d, 128, 0, stream>>>(wf, hidden, (1 << d) - 1);
  unary_kernel<<<NNODE, 64, 0, stream>>>(wf, hidden, unary, f2n);
  edge_kernel<<<dim3(32, 64), 256, 0, stream>>>(hidden, wf, edge);
  for (int d = NDEPTH; d >= 0; --d)
    up_kernel<<<1 << d, 64, 0, stream>>>(unary, edge, v2f, f2p, (1 << d) - 1, d);
  for (int d = 1; d <= NDEPTH; ++d)
    down_kernel<<<1 << d, 64, 0, stream>>>(unary, edge, f2p, f2n, (1 << d) - 1);
  final_kernel<<<NNODE, 64, 0, stream>>>(v2f, f2n, flag, d_out);
}